// Round 14
// baseline (279.672 us; speedup 1.0000x reference)
//
#include <hip/hip_runtime.h>
#include <hip/hip_bf16.h>
#include <stdint.h>

#define BLOCK 256
#define TPB 256            // fused threads/block
#define SROWS 128          // fused rows per block
#define MAXO 64
#define TK_THREADS 1024
#define CK_MAX 4096
#define NSL 8              // histogram slices per image (K4a grid.x)

// ---------------- K1: per-object argmax over P (block per (n,o)) + init ----------------
__global__ void match_object_kernel(const float* __restrict__ boxes,
                                    const float* __restrict__ priors,
                                    int* __restrict__ pfop,
                                    float* __restrict__ acc, int* __restrict__ n_pos,
                                    unsigned* __restrict__ done, int N, int P, int O) {
    __shared__ unsigned long long swm[4];
    int idx = blockIdx.x, tid = threadIdx.x;
    if (idx == 0) {                       // init for later dispatches (stream-ordered)
        for (int j = tid; j < N; j += BLOCK) n_pos[j] = 0;
        if (tid >= 64 && tid < 67) acc[tid - 64] = 0.f;
        if (tid == 96) *done = 0u;
    }
    const float* b = boxes + (size_t)idx * 4;
    float bx0 = b[0], by0 = b[1], bx1 = b[2], by1 = b[3];
    float areaa = (bx1 - bx0) * (by1 - by0);

    unsigned long long best = 0ULL;
    for (int p = tid; p < P; p += BLOCK) {
        float4 pr = ((const float4*)priors)[p];
        float px0 = pr.x - pr.z * 0.5f, py0 = pr.y - pr.w * 0.5f;
        float px1 = pr.x + pr.z * 0.5f, py1 = pr.y + pr.w * 0.5f;
        float areab = (px1 - px0) * (py1 - py0);
        float ltx = fmaxf(bx0, px0), lty = fmaxf(by0, py0);
        float rbx = fminf(bx1, px1), rby = fminf(by1, py1);
        float wx = fmaxf(rbx - ltx, 0.f), wy = fmaxf(rby - lty, 0.f);
        float inter = wx * wy;
        float iou = inter / (areaa + areab - inter);
        unsigned long long cand = (((unsigned long long)__float_as_uint(iou)) << 32) |
                                  (unsigned long long)(0xFFFFFFFFu - (unsigned)p);
        if (cand > best) best = cand;     // larger iou; tie -> smaller p (numpy first)
    }
    #pragma unroll
    for (int off = 32; off >= 1; off >>= 1) {
        unsigned long long other = __shfl_down(best, off);
        if (other > best) best = other;
    }
    if ((tid & 63) == 0) swm[tid >> 6] = best;
    __syncthreads();
    if (tid == 0) {
        unsigned long long r = swm[0];
        for (int w = 1; w < BLOCK / 64; ++w) if (swm[w] > r) r = swm[w];
        pfop[idx] = (int)(0xFFFFFFFFu - (unsigned)(r & 0xFFFFFFFFull));
    }
}

// ---------------- K2+K3 fused (R12 exact): LDS-bounce, thread-per-row ----------------
__global__ void __launch_bounds__(TPB)
fused_staged_kernel(const float* __restrict__ boxes,
                    const float* __restrict__ priors,
                    const float* __restrict__ locs,
                    const int* __restrict__ labels,
                    const int* __restrict__ pfop,
                    const float* __restrict__ scores,
                    float* __restrict__ ce_neg,
                    float* __restrict__ pb_loc, float* __restrict__ pb_pce,
                    int* __restrict__ pb_npos,
                    int N, int P, int O) {
    __shared__ float4 sstage4[SROWS * 81 / 4];   // 2592 float4 = 41,472 B
    __shared__ float sbx[MAXO * 4];
    __shared__ int   spf[MAXO];
    __shared__ int   slab[MAXO];
    __shared__ float sl[4], sp[4]; __shared__ int sn[4];
    const float* sstage = (const float*)sstage4;

    int n = blockIdx.y, bx = blockIdx.x, tid = threadIdx.x;
    int w = tid >> 6, lane = tid & 63;
    int p0 = bx * SROWS;
    int rows = P - p0; if (rows > SROWS) rows = SROWS;   // rows % 4 == 0 (P % 4 == 0)
    int p = p0 + tid;
    bool valid = tid < rows;                             // threads >= 128 always invalid
    size_t t = (size_t)n * P + p;

    for (int i = tid; i < O * 4; i += TPB) sbx[i] = boxes[(size_t)n * O * 4 + i];
    for (int i = tid; i < O; i += TPB) { spf[i] = pfop[n * O + i]; slab[i] = labels[n * O + i]; }
    float4 pr = make_float4(0.f, 0.f, 1.f, 1.f);
    float4 pl = make_float4(0.f, 0.f, 0.f, 0.f);
    if (valid) {
        pr = ((const float4*)priors)[p];
        pl = ((const float4*)locs)[t];
    }

    const float4* chunk = (const float4*)(scores + ((size_t)n * P + p0) * 81);
    if (rows == SROWS) {                               // 2592 = 10*256 + 32
        #pragma unroll
        for (int j = 0; j < 10; ++j)
            sstage4[j * TPB + tid] = chunk[j * TPB + tid];
        if (tid < 32)
            sstage4[10 * TPB + tid] = chunk[10 * TPB + tid];
    } else {
        int nf4 = rows * 81 / 4;
        for (int j = 0; j < 11; ++j) {
            int idx = j * TPB + tid;
            if (idx < nf4) sstage4[idx] = chunk[idx];
        }
    }
    __syncthreads();

    float my_loc = 0.f, my_pce = 0.f; int my_pos = 0;
    if (valid) {
        const float* row = sstage + tid * 81;          // bank stride 17: conflict-free
        float e = 0.f;
        #pragma unroll
        for (int j = 0; j < 81; ++j) e += __expf(row[j]);

        float px0 = pr.x - pr.z * 0.5f, py0 = pr.y - pr.w * 0.5f;
        float px1 = pr.x + pr.z * 0.5f, py1 = pr.y + pr.w * 0.5f;
        float areab = (px1 - px0) * (py1 - py0);
        float best = -1.f; int bo = 0;
        for (int o = 0; o < O; ++o) {
            float x0 = sbx[o*4+0], y0 = sbx[o*4+1], x1 = sbx[o*4+2], y1 = sbx[o*4+3];
            float ltx = fmaxf(x0, px0), lty = fmaxf(y0, py0);
            float rbx = fminf(x1, px1), rby = fminf(y1, py1);
            float wx = fmaxf(rbx - ltx, 0.f), wy = fmaxf(rby - lty, 0.f);
            float inter = wx * wy;
            float areao = (x1 - x0) * (y1 - y0);
            float iou = inter / (areao + areab - inter);
            if (iou > best) { best = iou; bo = o; }
        }
        int fo = -1;
        for (int o = 0; o < O; ++o) if (spf[o] == p) fo = o;
        int obj; float ov;
        if (fo >= 0) { obj = fo; ov = 1.0f; }
        else         { obj = bo; ov = best; }
        int tc = (ov < 0.5f) ? 0 : slab[obj];

        float stc = row[tc];
        float ce = logf(e) - stc;
        bool pos = (tc != 0);
        ce_neg[t] = pos ? 0.f : ce;
        if (pos) {
            my_pce = ce; my_pos = 1;
            float x0 = sbx[obj*4+0], y0 = sbx[obj*4+1], x1 = sbx[obj*4+2], y1 = sbx[obj*4+3];
            float cx = (x0 + x1) * 0.5f, cy = (y0 + y1) * 0.5f;
            float bw = x1 - x0, bh = y1 - y0;
            float g0 = (cx - pr.x) / (pr.z / 10.0f);
            float g1 = (cy - pr.y) / (pr.w / 10.0f);
            float g2 = logf(bw / pr.z) * 5.0f;
            float g3 = logf(bh / pr.w) * 5.0f;
            my_loc = fabsf(pl.x-g0) + fabsf(pl.y-g1) + fabsf(pl.z-g2) + fabsf(pl.w-g3);
        }
    }

    #pragma unroll
    for (int off = 32; off >= 1; off >>= 1) {
        my_loc += __shfl_down(my_loc, off);
        my_pce += __shfl_down(my_pce, off);
        my_pos += __shfl_down(my_pos, off);
    }
    if (lane == 0) { sl[w] = my_loc; sp[w] = my_pce; sn[w] = my_pos; }
    __syncthreads();
    if (tid == 0) {
        int npb = gridDim.x;
        pb_loc[n * npb + bx]  = (sl[0] + sl[1]) + (sl[2] + sl[3]);
        pb_pce[n * npb + bx]  = (sp[0] + sp[1]) + (sp[2] + sp[3]);
        pb_npos[n * npb + bx] = sn[0] + sn[1] + sn[2] + sn[3];
    }
}

// ---------------- K4a: per-slice histogram (counts + f32 sums), all CUs busy ----------------
// Each block owns its private output copy: LDS-zeroed, plain global stores. No
// cross-block contention (R8's global-atomic trap avoided by construction).
__global__ void hist_kernel(const float* __restrict__ ce_neg,
                            int* __restrict__ hist8, float* __restrict__ hsum8,
                            int N, int P) {
    __shared__ int   hc[4096];
    __shared__ float hs[4096];
    int n = blockIdx.y, s = blockIdx.x, tid = threadIdx.x;
    for (int b = tid; b < 4096; b += TK_THREADS) { hc[b] = 0; hs[b] = 0.f; }
    __syncthreads();
    int per = (P + NSL - 1) / NSL;
    int lo = s * per, hi = lo + per; if (hi > P) hi = P;
    const float* row = ce_neg + (size_t)n * P;
    for (int i = lo + tid; i < hi; i += TK_THREADS) {
        float v = row[i];
        unsigned key = __float_as_uint(v);
        int bin = (int)(key >> 20);
        atomicAdd(&hc[bin], 1);
        atomicAdd(&hs[bin], v);
    }
    __syncthreads();
    size_t base = ((size_t)n * NSL + s) * 4096;
    for (int b = tid; b < 4096; b += TK_THREADS) {
        hist8[base + b] = hc[b];
        hsum8[base + b] = hs[b];
    }
}

// ---------------- K4b: histogram-driven top-k + final combine (fast path) ----------------
// Reduce 8 slice-hists (coalesced int4/float4), threshold via shuffle suffix-scan
// (R11-verified), above-bin sum from per-bin f32 sums (no P-pass), ONE P-pass to
// collect boundary-bin keys (guard: falls back to R7 two-pass if bin > CK_MAX).
// Refine/rank/tie semantics identical to R7 (equal-key subsets sum identically).
__global__ void topk_hist_final(const float* __restrict__ ce_neg,
                                int* __restrict__ n_pos,
                                const float* __restrict__ pb_loc,
                                const float* __restrict__ pb_pce,
                                const int* __restrict__ pb_npos, int npb,
                                const int* __restrict__ hist8,
                                const float* __restrict__ hsum8,
                                float* __restrict__ acc, unsigned* __restrict__ done,
                                int N, int P, unsigned* __restrict__ out) {
    __shared__ unsigned ckeys[CK_MAX];
    __shared__ int  part[256];
    __shared__ int  wtot[16];
    __shared__ float shf[16];
    __shared__ int s_tb, s_ca, s_tb2, s_ca2, s_cnt, s_np, s_htb;
    __shared__ float s_above;
    int n = blockIdx.x, tid = threadIdx.x;
    int w = tid >> 6, lane = tid & 63;

    // ---- pb partial reduce (wave 0) ----
    if (tid < 64) {
        float psl = 0.f, psp = 0.f; int psn = 0;
        for (int i = tid; i < npb; i += 64) {
            psl += pb_loc[n * npb + i];
            psp += pb_pce[n * npb + i];
            psn += pb_npos[n * npb + i];
        }
        #pragma unroll
        for (int off = 32; off >= 1; off >>= 1) {
            psl += __shfl_down(psl, off);
            psp += __shfl_down(psp, off);
            psn += __shfl_down(psn, off);
        }
        if (tid == 0) {
            s_np = psn;
            n_pos[n] = psn;                           // plain store; fenced before done++
            if (psl != 0.f) atomicAdd(&acc[0], psl);
            if (psp != 0.f) atomicAdd(&acc[1], psp);
        }
    }
    __syncthreads();
    int k = 3 * s_np; if (k > P) k = P;
    float bsum = 0.f;

    if (k > 0) {
        // ---- combine 8 slice histograms: thread tid owns bins tid*4..tid*4+3 ----
        int4   hcv = make_int4(0, 0, 0, 0);
        float4 hfv = make_float4(0.f, 0.f, 0.f, 0.f);
        for (int s = 0; s < NSL; ++s) {
            size_t base = ((size_t)n * NSL + s) * 4096;
            int4   c = ((const int4*)(hist8 + base))[tid];
            float4 f = ((const float4*)(hsum8 + base))[tid];
            hcv.x += c.x; hcv.y += c.y; hcv.z += c.z; hcv.w += c.w;
            hfv.x += f.x; hfv.y += f.y; hfv.z += f.z; hfv.w += f.w;
        }
        int h0 = hcv.x, h1 = hcv.y, h2 = hcv.z, h3 = hcv.w;

        // ---- threshold bin: shuffle suffix-scan (R11-verified) ----
        int lsum = h0 + h1 + h2 + h3;
        int si = lsum;
        #pragma unroll
        for (int off = 1; off < 64; off <<= 1) {
            int tv = __shfl_down(si, off);
            if (lane + off < 64) si += tv;
        }
        if (lane == 0) wtot[w] = si;
        __syncthreads();
        if (tid < 16) {
            int ov = wtot[tid];
            int v = ov;
            #pragma unroll
            for (int off = 1; off < 16; off <<= 1) {
                int tv = __shfl_down(v, off);
                if (lane + off < 16) v += tv;
            }
            wtot[tid] = v - ov;
        }
        if (tid == 0) s_cnt = 0;
        if (tid < 256) part[tid] = 0;
        __syncthreads();
        int b0 = tid * 4;
        int sfx = wtot[w] + (si - lsum);
        int sf3 = sfx, sf2 = sf3 + h3, sf1 = sf2 + h2, sf0 = sf1 + h1;
        if (sf0 < k && k <= sf0 + h0) { s_tb = b0;   s_ca = sf0; s_htb = h0; }
        if (sf1 < k && k <= sf1 + h1) { s_tb = b0+1; s_ca = sf1; s_htb = h1; }
        if (sf2 < k && k <= sf2 + h2) { s_tb = b0+2; s_ca = sf2; s_htb = h2; }
        if (sf3 < k && k <= sf3 + h3) { s_tb = b0+3; s_ca = sf3; s_htb = h3; }
        __syncthreads();
        int tb = s_tb, kk = k - s_ca, mtb = s_htb;

        // ---- above-bin sum from per-bin f32 sums (no P-pass) ----
        float ab = 0.f;
        ab += (b0     > tb) ? hfv.x : 0.f;
        ab += (b0 + 1 > tb) ? hfv.y : 0.f;
        ab += (b0 + 2 > tb) ? hfv.z : 0.f;
        ab += (b0 + 3 > tb) ? hfv.w : 0.f;
        #pragma unroll
        for (int off = 32; off >= 1; off >>= 1) ab += __shfl_down(ab, off);
        if (lane == 0) shf[w] = ab;
        __syncthreads();
        if (tid == 0) {
            float tot = 0.f;
            for (int i = 0; i < 16; ++i) tot += shf[i];
            s_above = tot;
        }
        __syncthreads();

        const float* row = ce_neg + (size_t)n * P;
        float ssum = 0.f;
        if (mtb <= CK_MAX) {
            // ---- ONE pass: collect ALL bin-tb keys + sub-bin counts ----
            for (int i = tid; i < P; i += TK_THREADS) {
                unsigned key = __float_as_uint(row[i]);
                if ((int)(key >> 20) == tb) {
                    atomicAdd(&part[(key >> 12) & 255u], 1);
                    int slot = atomicAdd(&s_cnt, 1);
                    ckeys[slot] = key;                 // slot < mtb <= CK_MAX
                }
            }
            __syncthreads();
            if (tid < 256) {
                int cum = 0;
                for (int b = tid + 1; b < 256; ++b) cum += part[b];
                int h = part[tid];
                if (cum < kk && kk <= cum + h) { s_tb2 = tid; s_ca2 = cum; }
            }
            __syncthreads();
            int tb2 = s_tb2, kk2 = kk - s_ca2;
            int m = s_cnt;
            for (int i = tid; i < m; i += TK_THREADS) {
                unsigned key = ckeys[i];
                int b2 = (key >> 12) & 255u;
                if (b2 > tb2) ssum += __uint_as_float(key);
                else if (b2 == tb2) {
                    int rank = 0;
                    for (int j = 0; j < m; ++j) {
                        unsigned kj = ckeys[j];
                        if (((kj >> 12) & 255u) == (unsigned)tb2)
                            rank += (kj > key) || (kj == key && j < i);
                    }
                    if (rank < kk2) ssum += __uint_as_float(key);
                }
            }
        } else {
            // ---- safe fallback (R7 two-pass, reading global row) ----
            for (int i = tid; i < P; i += TK_THREADS) {
                unsigned key = __float_as_uint(row[i]);
                if ((int)(key >> 20) == tb) atomicAdd(&part[(key >> 12) & 255u], 1);
            }
            __syncthreads();
            if (tid < 256) {
                int cum = 0;
                for (int b = tid + 1; b < 256; ++b) cum += part[b];
                int h = part[tid];
                if (cum < kk && kk <= cum + h) { s_tb2 = tid; s_ca2 = cum; }
            }
            __syncthreads();
            int tb2 = s_tb2, kk2 = kk - s_ca2;
            for (int i = tid; i < P; i += TK_THREADS) {
                unsigned key = __float_as_uint(row[i]);
                if ((int)(key >> 20) == tb) {
                    int b2 = (key >> 12) & 255u;
                    if (b2 > tb2) ssum += __uint_as_float(key);
                    else if (b2 == tb2) {
                        int slot = atomicAdd(&s_cnt, 1);
                        if (slot < CK_MAX) ckeys[slot] = key;
                    }
                }
            }
            __syncthreads();
            int m = s_cnt; if (m > CK_MAX) m = CK_MAX;
            for (int i = tid; i < m; i += TK_THREADS) {
                unsigned key = ckeys[i];
                int rank = 0;
                for (int j = 0; j < m; ++j) {
                    unsigned kj = ckeys[j];
                    rank += (kj > key) || (kj == key && j < i);
                }
                if (rank < kk2) ssum += __uint_as_float(key);
            }
        }
        #pragma unroll
        for (int off = 32; off >= 1; off >>= 1) ssum += __shfl_down(ssum, off);
        __syncthreads();
        if ((tid & 63) == 0) shf[tid >> 6] = ssum;
        __syncthreads();
        if (tid == 0) {
            float tot = 0.f;
            for (int i = 0; i < 16; ++i) tot += shf[i];
            bsum = tot + s_above;
        }
    }

    if (tid == 0) {
        if (bsum != 0.f) atomicAdd(&acc[2], bsum);
        __threadfence();
        unsigned old = atomicAdd(done, 1u);
        if (old == (unsigned)(N - 1)) {
            float a0 = atomicAdd(&acc[0], 0.f);
            float a1 = atomicAdd(&acc[1], 0.f);
            float a2 = atomicAdd(&acc[2], 0.f);
            int tot = 0;
            for (int i = 0; i < N; ++i) tot += n_pos[i];
            float npos = (float)tot;
            float conf = (a2 + a1) / npos;
            float loc  = a0 / (4.f * npos);
            float loss = conf + loc;
            unsigned ub = __float_as_uint(loss);
            unsigned r = (ub + 0x7FFFu + ((ub >> 16) & 1u)) >> 16;  // bf16 RNE
            out[0] = (r << 16) | r;
        }
    }
}

// ---------------- fallback K2: per-prior match -> tcarr (any C path) ----------------
__global__ void match_prior_kernel(const float* __restrict__ boxes,
                                   const float* __restrict__ priors,
                                   const float* __restrict__ locs,
                                   const int* __restrict__ labels,
                                   const int* __restrict__ pfop,
                                   int* __restrict__ tcarr,
                                   float* __restrict__ acc, int* __restrict__ n_pos,
                                   int N, int P, int O) {
    __shared__ float sbx[MAXO * 4];
    __shared__ float sarea[MAXO];
    __shared__ int   spf[MAXO];
    __shared__ int   slab[MAXO];
    int n = blockIdx.y, tid = threadIdx.x;
    if (tid < O * 4) sbx[tid] = boxes[(size_t)n * O * 4 + tid];
    if (tid >= 128 && tid < 128 + O) spf[tid - 128]  = pfop[n * O + (tid - 128)];
    if (tid >= 192 && tid < 192 + O) slab[tid - 192] = labels[n * O + (tid - 192)];
    __syncthreads();
    if (tid < O)
        sarea[tid] = (sbx[tid*4+2] - sbx[tid*4+0]) * (sbx[tid*4+3] - sbx[tid*4+1]);
    __syncthreads();

    int p = blockIdx.x * BLOCK + tid;
    bool valid = p < P;
    float my_loc = 0.f; int my_pos = 0;
    if (valid) {
        float4 pr = ((const float4*)priors)[p];
        float px0 = pr.x - pr.z * 0.5f, py0 = pr.y - pr.w * 0.5f;
        float px1 = pr.x + pr.z * 0.5f, py1 = pr.y + pr.w * 0.5f;
        float areab = (px1 - px0) * (py1 - py0);

        float best = -1.f; int bo = 0;
        for (int o = 0; o < O; ++o) {
            float ltx = fmaxf(sbx[o*4+0], px0);
            float lty = fmaxf(sbx[o*4+1], py0);
            float rbx = fminf(sbx[o*4+2], px1);
            float rby = fminf(sbx[o*4+3], py1);
            float wx = fmaxf(rbx - ltx, 0.f), wy = fmaxf(rby - lty, 0.f);
            float inter = wx * wy;
            float iou = inter / (sarea[o] + areab - inter);
            if (iou > best) { best = iou; bo = o; }
        }
        int fo = -1;
        for (int o = 0; o < O; ++o) if (spf[o] == p) fo = o;
        int obj; float ov;
        if (fo >= 0) { obj = fo; ov = 1.0f; }
        else         { obj = bo; ov = best; }
        int lab = slab[obj];
        int tc = (ov < 0.5f) ? 0 : lab;
        tcarr[(size_t)n * P + p] = tc;
        if (tc != 0) {
            my_pos = 1;
            float x0 = sbx[obj*4+0], y0 = sbx[obj*4+1], x1 = sbx[obj*4+2], y1 = sbx[obj*4+3];
            float cx = (x0 + x1) * 0.5f, cy = (y0 + y1) * 0.5f;
            float w = x1 - x0, h = y1 - y0;
            float g0 = (cx - pr.x) / (pr.z / 10.0f);
            float g1 = (cy - pr.y) / (pr.w / 10.0f);
            float g2 = logf(w / pr.z) * 5.0f;
            float g3 = logf(h / pr.w) * 5.0f;
            const float* pl = locs + ((size_t)n * P + p) * 4;
            my_loc = fabsf(pl[0]-g0) + fabsf(pl[1]-g1) + fabsf(pl[2]-g2) + fabsf(pl[3]-g3);
        }
    }
    #pragma unroll
    for (int off = 32; off >= 1; off >>= 1) {
        my_loc += __shfl_down(my_loc, off);
        my_pos += __shfl_down(my_pos, off);
    }
    if ((tid & 63) == 0 && my_pos) {
        atomicAdd(&acc[0], my_loc);
        atomicAdd(&n_pos[n], my_pos);
    }
}

// ---------------- generic fallback (any C) ----------------
__global__ void loss_generic_kernel(const float* __restrict__ scores,
                                    const int* __restrict__ tcarr,
                                    float* __restrict__ ce_neg, float* __restrict__ acc,
                                    int NP, int C) {
    int t = blockIdx.x * blockDim.x + threadIdx.x;
    if (t >= NP) return;
    int tc = tcarr[t];
    const float* s = scores + (size_t)t * C;
    float m = -3.0e38f;
    for (int j = 0; j < C; ++j) m = fmaxf(m, s[j]);
    float l = 0.f, stc = 0.f;
    for (int j = 0; j < C; ++j) {
        float v = s[j];
        l += __expf(v - m);
        if (j == tc) stc = v;
    }
    float ce = m + logf(l) - stc;
    bool pos = (tc != 0);
    ce_neg[t] = pos ? 0.f : ce;
    if (pos) atomicAdd(&acc[1], ce);
}

// ---------------- K4 fallback: R7-exact top-k (npb==0 path only) ----------------
__global__ void topk_final_kernel(const float* __restrict__ ce_neg,
                                  int* __restrict__ n_pos,
                                  float* __restrict__ acc, unsigned* __restrict__ done,
                                  int N, int P, unsigned* __restrict__ out) {
    __shared__ unsigned skeys[8732];
    __shared__ int hist[4096];
    __shared__ int part[1024];
    __shared__ int s_tb, s_ca, s_tb2, s_ca2, s_cnt;
    __shared__ float shf[16];
    int n = blockIdx.x, tid = threadIdx.x;
    int k = 3 * n_pos[n]; if (k > P) k = P;
    float bsum = 0.f;

    if (k > 0) {
        const float* row = ce_neg + (size_t)n * P;
        for (int i = tid; i < P; i += TK_THREADS) skeys[i] = __float_as_uint(row[i]);
        #pragma unroll
        for (int b = 0; b < 4; ++b) hist[tid * 4 + b] = 0;
        __syncthreads();

        for (int i = tid; i < P; i += TK_THREADS) atomicAdd(&hist[skeys[i] >> 20], 1);
        __syncthreads();
        int h0 = hist[tid*4], h1 = hist[tid*4+1], h2 = hist[tid*4+2], h3 = hist[tid*4+3];
        part[tid] = h0 + h1 + h2 + h3;
        __syncthreads();
        for (int s = 1; s < 1024; s <<= 1) {
            int v = part[tid] + ((tid + s < 1024) ? part[tid + s] : 0);
            __syncthreads();
            part[tid] = v;
            __syncthreads();
        }
        int sfx = (tid + 1 < 1024) ? part[tid + 1] : 0;
        int sf3 = sfx, sf2 = sfx + h3, sf1 = sf2 + h2, sf0 = sf1 + h1;
        if (sf0 < k && k <= sf0 + h0) { s_tb = tid*4;   s_ca = sf0; }
        if (sf1 < k && k <= sf1 + h1) { s_tb = tid*4+1; s_ca = sf1; }
        if (sf2 < k && k <= sf2 + h2) { s_tb = tid*4+2; s_ca = sf2; }
        if (sf3 < k && k <= sf3 + h3) { s_tb = tid*4+3; s_ca = sf3; }
        __syncthreads();
        int tb = s_tb, kk = k - s_ca;

        if (tid < 256) part[tid] = 0;
        __syncthreads();
        float ssum = 0.f;
        for (int i = tid; i < P; i += TK_THREADS) {
            unsigned key = skeys[i];
            int bin = key >> 20;
            if (bin > tb) ssum += __uint_as_float(key);
            else if (bin == tb) atomicAdd(&part[(key >> 12) & 255u], 1);
        }
        __syncthreads();
        if (tid < 256) {
            int cum = 0;
            for (int b = tid + 1; b < 256; ++b) cum += part[b];
            int h = part[tid];
            if (cum < kk && kk <= cum + h) { s_tb2 = tid; s_ca2 = cum; }
        }
        if (tid == 0) s_cnt = 0;
        __syncthreads();
        int tb2 = s_tb2, kk2 = kk - s_ca2;

        unsigned* ckeys = (unsigned*)hist;
        for (int i = tid; i < P; i += TK_THREADS) {
            unsigned key = skeys[i];
            if ((int)(key >> 20) == tb) {
                int b2 = (key >> 12) & 255u;
                if (b2 > tb2) ssum += __uint_as_float(key);
                else if (b2 == tb2) {
                    int slot = atomicAdd(&s_cnt, 1);
                    if (slot < CK_MAX) ckeys[slot] = key;
                }
            }
        }
        __syncthreads();
        int m = s_cnt; if (m > CK_MAX) m = CK_MAX;
        for (int i = tid; i < m; i += TK_THREADS) {
            unsigned key = ckeys[i];
            int rank = 0;
            for (int j = 0; j < m; ++j) {
                unsigned kj = ckeys[j];
                rank += (kj > key) || (kj == key && j < i);
            }
            if (rank < kk2) ssum += __uint_as_float(key);
        }
        #pragma unroll
        for (int off = 32; off >= 1; off >>= 1) ssum += __shfl_down(ssum, off);
        __syncthreads();
        if ((tid & 63) == 0) shf[tid >> 6] = ssum;
        __syncthreads();
        float tot = 0.f;
        for (int i = 0; i < 16; ++i) tot += shf[i];
        bsum = tot;
    }

    if (tid == 0) {
        if (bsum != 0.f) atomicAdd(&acc[2], bsum);
        __threadfence();
        unsigned old = atomicAdd(done, 1u);
        if (old == (unsigned)(N - 1)) {
            float a0 = atomicAdd(&acc[0], 0.f);
            float a1 = atomicAdd(&acc[1], 0.f);
            float a2 = atomicAdd(&acc[2], 0.f);
            int tot = 0;
            for (int i = 0; i < N; ++i) tot += n_pos[i];
            float npos = (float)tot;
            float conf = (a2 + a1) / npos;
            float loc  = a0 / (4.f * npos);
            float loss = conf + loc;
            unsigned ub = __float_as_uint(loss);
            unsigned r = (ub + 0x7FFFu + ((ub >> 16) & 1u)) >> 16;  // bf16 RNE
            out[0] = (r << 16) | r;
        }
    }
}

extern "C" void kernel_launch(void* const* d_in, const int* in_sizes, int n_in,
                              void* d_out, int out_size, void* d_ws, size_t ws_size,
                              hipStream_t stream) {
    const float* locs   = (const float*)d_in[0];
    const float* scores = (const float*)d_in[1];
    const float* boxes  = (const float*)d_in[2];
    const int*   labels = (const int*)d_in[3];
    const float* priors = (const float*)d_in[4];

    int P = in_sizes[4] / 4;
    long long NPl = in_sizes[0] / 4;
    int N = (int)(NPl / P);
    int C = (int)((long long)in_sizes[1] / NPl);
    int O = in_sizes[3] / N;
    size_t NP = (size_t)N * P;
    int gx = (P + SROWS - 1) / SROWS;

    char* ws = (char*)d_ws;
    float*    acc    = (float*)ws;     ws += 16;
    unsigned* done   = (unsigned*)ws;  ws += 16;
    int*      n_pos  = (int*)ws;       ws += (size_t)N * 4;
    int*      pfop   = (int*)ws;       ws += (size_t)N * O * 4;
    int*      hist8  = (int*)ws;       ws += (size_t)N * NSL * 4096 * 4;
    float*    hsum8  = (float*)ws;     ws += (size_t)N * NSL * 4096 * 4;
    float*    pb_loc = (float*)ws;     ws += (size_t)N * gx * 4;
    float*    pb_pce = (float*)ws;     ws += (size_t)N * gx * 4;
    int*      pb_npos= (int*)ws;       ws += (size_t)N * gx * 4;
    int*      tcarr  = (int*)ws;       ws += NP * 4;
    float*    ce_neg = (float*)ws;     ws += NP * 4;

    match_object_kernel<<<N * O, BLOCK, 0, stream>>>(boxes, priors, pfop, acc, n_pos,
                                                     done, N, P, O);
    if (C == 81 && (P % 4) == 0 && O <= MAXO && P <= NSL * 8732) {
        fused_staged_kernel<<<dim3(gx, N), TPB, 0, stream>>>(
            boxes, priors, locs, labels, pfop, scores, ce_neg,
            pb_loc, pb_pce, pb_npos, N, P, O);
        hist_kernel<<<dim3(NSL, N), TK_THREADS, 0, stream>>>(ce_neg, hist8, hsum8, N, P);
        topk_hist_final<<<N, TK_THREADS, 0, stream>>>(ce_neg, n_pos,
                                                      pb_loc, pb_pce, pb_npos, gx,
                                                      hist8, hsum8,
                                                      acc, done, N, P, (unsigned*)d_out);
    } else {
        int gbx = (P + BLOCK - 1) / BLOCK;
        match_prior_kernel<<<dim3(gbx, N), BLOCK, 0, stream>>>(boxes, priors, locs, labels,
                                                               pfop, tcarr, acc, n_pos, N, P, O);
        loss_generic_kernel<<<(int)((NP + BLOCK - 1) / BLOCK), BLOCK, 0, stream>>>(
            scores, tcarr, ce_neg, acc, (int)NP, C);
        topk_final_kernel<<<N, TK_THREADS, 0, stream>>>(ce_neg, n_pos, acc, done, N, P,
                                                        (unsigned*)d_out);
    }
}

// Round 15
// 182.003 us; speedup vs baseline: 1.5366x; 1.5366x over previous
//
#include <hip/hip_runtime.h>
#include <hip/hip_bf16.h>
#include <stdint.h>

#define BLOCK 256
#define SBLOCK 128
#define MAXO 64
#define TK_THREADS 1024
#define CK_MAX 4096

// ---------------- K1: per-object argmax over P (block per (n,o)) + init ----------------
__global__ void match_object_kernel(const float* __restrict__ boxes,
                                    const float* __restrict__ priors,
                                    int* __restrict__ pfop,
                                    float* __restrict__ acc, int* __restrict__ n_pos,
                                    unsigned* __restrict__ done, int N, int P, int O) {
    __shared__ unsigned long long swm[4];
    int idx = blockIdx.x, tid = threadIdx.x;
    if (idx == 0) {                       // init for later dispatches (stream-ordered)
        for (int j = tid; j < N; j += BLOCK) n_pos[j] = 0;
        if (tid >= 64 && tid < 67) acc[tid - 64] = 0.f;
        if (tid == 96) *done = 0u;
    }
    const float* b = boxes + (size_t)idx * 4;
    float bx0 = b[0], by0 = b[1], bx1 = b[2], by1 = b[3];
    float areaa = (bx1 - bx0) * (by1 - by0);

    unsigned long long best = 0ULL;
    for (int p = tid; p < P; p += BLOCK) {
        float4 pr = ((const float4*)priors)[p];
        float px0 = pr.x - pr.z * 0.5f, py0 = pr.y - pr.w * 0.5f;
        float px1 = pr.x + pr.z * 0.5f, py1 = pr.y + pr.w * 0.5f;
        float areab = (px1 - px0) * (py1 - py0);
        float ltx = fmaxf(bx0, px0), lty = fmaxf(by0, py0);
        float rbx = fminf(bx1, px1), rby = fminf(by1, py1);
        float wx = fmaxf(rbx - ltx, 0.f), wy = fmaxf(rby - lty, 0.f);
        float inter = wx * wy;
        float iou = inter / (areaa + areab - inter);
        unsigned long long cand = (((unsigned long long)__float_as_uint(iou)) << 32) |
                                  (unsigned long long)(0xFFFFFFFFu - (unsigned)p);
        if (cand > best) best = cand;     // larger iou; tie -> smaller p (numpy first)
    }
    #pragma unroll
    for (int off = 32; off >= 1; off >>= 1) {
        unsigned long long other = __shfl_down(best, off);
        if (other > best) best = other;
    }
    if ((tid & 63) == 0) swm[tid >> 6] = best;
    __syncthreads();
    if (tid == 0) {
        unsigned long long r = swm[0];
        for (int w = 1; w < BLOCK / 64; ++w) if (swm[w] > r) r = swm[w];
        pfop[idx] = (int)(0xFFFFFFFFu - (unsigned)(r & 0xFFFFFFFFull));
    }
}

// ---------------- K2+K3 fused (R7 exact, best measured): LDS-bounce, thread-per-row ----------------
__global__ void __launch_bounds__(SBLOCK)
fused_staged_kernel(const float* __restrict__ boxes,
                    const float* __restrict__ priors,
                    const float* __restrict__ locs,
                    const int* __restrict__ labels,
                    const int* __restrict__ pfop,
                    const float* __restrict__ scores,
                    float* __restrict__ ce_neg,
                    float* __restrict__ pb_loc, float* __restrict__ pb_pce,
                    int* __restrict__ pb_npos,
                    int N, int P, int O) {
    __shared__ float4 sstage4[SBLOCK * 81 / 4];   // 2592 float4 = 41,472 B
    __shared__ float sbx[MAXO * 4];
    __shared__ int   spf[MAXO];
    __shared__ int   slab[MAXO];
    __shared__ float sl[2], sp[2]; __shared__ int sn[2];
    const float* sstage = (const float*)sstage4;

    int n = blockIdx.y, bx = blockIdx.x, tid = threadIdx.x;
    int w = tid >> 6, lane = tid & 63;
    int p0 = bx * SBLOCK;
    int rows = P - p0; if (rows > SBLOCK) rows = SBLOCK;   // rows % 4 == 0 (P % 4 == 0)
    int p = p0 + tid;
    bool valid = tid < rows;
    size_t t = (size_t)n * P + p;

    // ---- metadata -> LDS (small), prior/loc -> regs ----
    for (int i = tid; i < O * 4; i += SBLOCK) sbx[i] = boxes[(size_t)n * O * 4 + i];
    for (int i = tid; i < O; i += SBLOCK) { spf[i] = pfop[n * O + i]; slab[i] = labels[n * O + i]; }
    float4 pr = make_float4(0.f, 0.f, 1.f, 1.f);
    float4 pl = make_float4(0.f, 0.f, 0.f, 0.f);
    if (valid) {
        pr = ((const float4*)priors)[p];
        pl = ((const float4*)locs)[t];
    }

    // ---- stage: coalesced float4 copy, identity layout (global chunk is contiguous) ----
    const float4* chunk = (const float4*)(scores + ((size_t)n * P + p0) * 81);
    if (rows == SBLOCK) {
        #pragma unroll
        for (int j = 0; j < 20; ++j)
            sstage4[j * SBLOCK + tid] = chunk[j * SBLOCK + tid];
        if (tid < 32)                                  // tail: 2560..2591
            sstage4[20 * SBLOCK + tid] = chunk[20 * SBLOCK + tid];
    } else {                                           // partial tile (one per image)
        int nf4 = rows * 81 / 4;
        for (int j = 0; j < 21; ++j) {
            int idx = j * SBLOCK + tid;
            if (idx < nf4) sstage4[idx] = chunk[idx];
        }
    }
    __syncthreads();

    // ---- consume: thread-per-row from LDS ----
    float my_loc = 0.f, my_pce = 0.f; int my_pos = 0;
    if (valid) {
        const float* row = sstage + tid * 81;          // bank stride 17: conflict-free
        float e = 0.f;
        #pragma unroll
        for (int j = 0; j < 81; ++j) e += __expf(row[j]);

        // match (v2 semantics): strict > = first index; forced match last-wins
        float px0 = pr.x - pr.z * 0.5f, py0 = pr.y - pr.w * 0.5f;
        float px1 = pr.x + pr.z * 0.5f, py1 = pr.y + pr.w * 0.5f;
        float areab = (px1 - px0) * (py1 - py0);
        float best = -1.f; int bo = 0;
        for (int o = 0; o < O; ++o) {                  // sbx reads wave-broadcast
            float x0 = sbx[o*4+0], y0 = sbx[o*4+1], x1 = sbx[o*4+2], y1 = sbx[o*4+3];
            float ltx = fmaxf(x0, px0), lty = fmaxf(y0, py0);
            float rbx = fminf(x1, px1), rby = fminf(y1, py1);
            float wx = fmaxf(rbx - ltx, 0.f), wy = fmaxf(rby - lty, 0.f);
            float inter = wx * wy;
            float areao = (x1 - x0) * (y1 - y0);
            float iou = inter / (areao + areab - inter);
            if (iou > best) { best = iou; bo = o; }
        }
        int fo = -1;
        for (int o = 0; o < O; ++o) if (spf[o] == p) fo = o;
        int obj; float ov;
        if (fo >= 0) { obj = fo; ov = 1.0f; }
        else         { obj = bo; ov = best; }
        int tc = (ov < 0.5f) ? 0 : slab[obj];

        float stc = row[tc];                           // free: already staged
        float ce = logf(e) - stc;
        bool pos = (tc != 0);
        ce_neg[t] = pos ? 0.f : ce;                    // coalesced store
        if (pos) {
            my_pce = ce; my_pos = 1;
            float x0 = sbx[obj*4+0], y0 = sbx[obj*4+1], x1 = sbx[obj*4+2], y1 = sbx[obj*4+3];
            float cx = (x0 + x1) * 0.5f, cy = (y0 + y1) * 0.5f;
            float bw = x1 - x0, bh = y1 - y0;
            float g0 = (cx - pr.x) / (pr.z / 10.0f);
            float g1 = (cy - pr.y) / (pr.w / 10.0f);
            float g2 = logf(bw / pr.z) * 5.0f;
            float g3 = logf(bh / pr.w) * 5.0f;
            my_loc = fabsf(pl.x-g0) + fabsf(pl.y-g1) + fabsf(pl.z-g2) + fabsf(pl.w-g3);
        }
    }

    // ---- block partials: plain stores, no atomics ----
    #pragma unroll
    for (int off = 32; off >= 1; off >>= 1) {
        my_loc += __shfl_down(my_loc, off);
        my_pce += __shfl_down(my_pce, off);
        my_pos += __shfl_down(my_pos, off);
    }
    if (lane == 0) { sl[w] = my_loc; sp[w] = my_pce; sn[w] = my_pos; }
    __syncthreads();
    if (tid == 0) {
        int npb = gridDim.x;
        pb_loc[n * npb + bx]  = sl[0] + sl[1];
        pb_pce[n * npb + bx]  = sp[0] + sp[1];
        pb_npos[n * npb + bx] = sn[0] + sn[1];
    }
}

// ---------------- fallback K2: per-prior match -> tcarr (any C path) ----------------
__global__ void match_prior_kernel(const float* __restrict__ boxes,
                                   const float* __restrict__ priors,
                                   const float* __restrict__ locs,
                                   const int* __restrict__ labels,
                                   const int* __restrict__ pfop,
                                   int* __restrict__ tcarr,
                                   float* __restrict__ acc, int* __restrict__ n_pos,
                                   int N, int P, int O) {
    __shared__ float sbx[MAXO * 4];
    __shared__ float sarea[MAXO];
    __shared__ int   spf[MAXO];
    __shared__ int   slab[MAXO];
    int n = blockIdx.y, tid = threadIdx.x;
    if (tid < O * 4) sbx[tid] = boxes[(size_t)n * O * 4 + tid];
    if (tid >= 128 && tid < 128 + O) spf[tid - 128]  = pfop[n * O + (tid - 128)];
    if (tid >= 192 && tid < 192 + O) slab[tid - 192] = labels[n * O + (tid - 192)];
    __syncthreads();
    if (tid < O)
        sarea[tid] = (sbx[tid*4+2] - sbx[tid*4+0]) * (sbx[tid*4+3] - sbx[tid*4+1]);
    __syncthreads();

    int p = blockIdx.x * BLOCK + tid;
    bool valid = p < P;
    float my_loc = 0.f; int my_pos = 0;
    if (valid) {
        float4 pr = ((const float4*)priors)[p];
        float px0 = pr.x - pr.z * 0.5f, py0 = pr.y - pr.w * 0.5f;
        float px1 = pr.x + pr.z * 0.5f, py1 = pr.y + pr.w * 0.5f;
        float areab = (px1 - px0) * (py1 - py0);

        float best = -1.f; int bo = 0;
        for (int o = 0; o < O; ++o) {
            float ltx = fmaxf(sbx[o*4+0], px0);
            float lty = fmaxf(sbx[o*4+1], py0);
            float rbx = fminf(sbx[o*4+2], px1);
            float rby = fminf(sbx[o*4+3], py1);
            float wx = fmaxf(rbx - ltx, 0.f), wy = fmaxf(rby - lty, 0.f);
            float inter = wx * wy;
            float iou = inter / (sarea[o] + areab - inter);
            if (iou > best) { best = iou; bo = o; }
        }
        int fo = -1;
        for (int o = 0; o < O; ++o) if (spf[o] == p) fo = o;
        int obj; float ov;
        if (fo >= 0) { obj = fo; ov = 1.0f; }
        else         { obj = bo; ov = best; }
        int lab = slab[obj];
        int tc = (ov < 0.5f) ? 0 : lab;
        tcarr[(size_t)n * P + p] = tc;
        if (tc != 0) {
            my_pos = 1;
            float x0 = sbx[obj*4+0], y0 = sbx[obj*4+1], x1 = sbx[obj*4+2], y1 = sbx[obj*4+3];
            float cx = (x0 + x1) * 0.5f, cy = (y0 + y1) * 0.5f;
            float w = x1 - x0, h = y1 - y0;
            float g0 = (cx - pr.x) / (pr.z / 10.0f);
            float g1 = (cy - pr.y) / (pr.w / 10.0f);
            float g2 = logf(w / pr.z) * 5.0f;
            float g3 = logf(h / pr.w) * 5.0f;
            const float* pl = locs + ((size_t)n * P + p) * 4;
            my_loc = fabsf(pl[0]-g0) + fabsf(pl[1]-g1) + fabsf(pl[2]-g2) + fabsf(pl[3]-g3);
        }
    }
    #pragma unroll
    for (int off = 32; off >= 1; off >>= 1) {
        my_loc += __shfl_down(my_loc, off);
        my_pos += __shfl_down(my_pos, off);
    }
    if ((tid & 63) == 0 && my_pos) {
        atomicAdd(&acc[0], my_loc);
        atomicAdd(&n_pos[n], my_pos);
    }
}

// ---------------- generic fallback (any C) ----------------
__global__ void loss_generic_kernel(const float* __restrict__ scores,
                                    const int* __restrict__ tcarr,
                                    float* __restrict__ ce_neg, float* __restrict__ acc,
                                    int NP, int C) {
    int t = blockIdx.x * blockDim.x + threadIdx.x;
    if (t >= NP) return;
    int tc = tcarr[t];
    const float* s = scores + (size_t)t * C;
    float m = -3.0e38f;
    for (int j = 0; j < C; ++j) m = fmaxf(m, s[j]);
    float l = 0.f, stc = 0.f;
    for (int j = 0; j < C; ++j) {
        float v = s[j];
        l += __expf(v - m);
        if (j == tc) stc = v;
    }
    float ce = m + logf(l) - stc;
    bool pos = (tc != 0);
    ce_neg[t] = pos ? 0.f : ce;
    if (pos) atomicAdd(&acc[1], ce);
}

// ---------------- K4: R7-exact top-k sum per row + partial-reduce + final combine ----------------
__global__ void topk_final_kernel(const float* __restrict__ ce_neg,
                                  int* __restrict__ n_pos,
                                  const float* __restrict__ pb_loc,
                                  const float* __restrict__ pb_pce,
                                  const int* __restrict__ pb_npos, int npb,
                                  float* __restrict__ acc, unsigned* __restrict__ done,
                                  int N, int P, unsigned* __restrict__ out) {
    __shared__ unsigned skeys[8732];
    __shared__ int hist[4096];        // aliased as ckeys later
    __shared__ int part[1024];
    __shared__ int s_tb, s_ca, s_tb2, s_ca2, s_cnt, s_np;
    __shared__ float shf[16];
    int n = blockIdx.x, tid = threadIdx.x;

    int k;
    if (npb > 0) {                    // fused path: reduce per-block partials (wave 0)
        if (tid < 64) {
            float psl = 0.f, psp = 0.f; int psn = 0;
            for (int i = tid; i < npb; i += 64) {
                psl += pb_loc[n * npb + i];
                psp += pb_pce[n * npb + i];
                psn += pb_npos[n * npb + i];
            }
            #pragma unroll
            for (int off = 32; off >= 1; off >>= 1) {
                psl += __shfl_down(psl, off);
                psp += __shfl_down(psp, off);
                psn += __shfl_down(psn, off);
            }
            if (tid == 0) {
                s_np = psn;
                n_pos[n] = psn;                       // plain store; fenced before done++
                if (psl != 0.f) atomicAdd(&acc[0], psl);
                if (psp != 0.f) atomicAdd(&acc[1], psp);
            }
        }
        __syncthreads();
        k = 3 * s_np;
    } else {
        k = 3 * n_pos[n];
    }
    if (k > P) k = P;
    float bsum = 0.f;

    if (k > 0) {                                      // block-uniform
        const float* row = ce_neg + (size_t)n * P;
        for (int i = tid; i < P; i += TK_THREADS) skeys[i] = __float_as_uint(row[i]);
        #pragma unroll
        for (int b = 0; b < 4; ++b) hist[tid * 4 + b] = 0;
        __syncthreads();

        for (int i = tid; i < P; i += TK_THREADS) atomicAdd(&hist[skeys[i] >> 20], 1);
        __syncthreads();
        int h0 = hist[tid*4], h1 = hist[tid*4+1], h2 = hist[tid*4+2], h3 = hist[tid*4+3];
        part[tid] = h0 + h1 + h2 + h3;
        __syncthreads();
        for (int s = 1; s < 1024; s <<= 1) {
            int v = part[tid] + ((tid + s < 1024) ? part[tid + s] : 0);
            __syncthreads();
            part[tid] = v;
            __syncthreads();
        }
        int sfx = (tid + 1 < 1024) ? part[tid + 1] : 0;
        int sf3 = sfx, sf2 = sfx + h3, sf1 = sf2 + h2, sf0 = sf1 + h1;
        if (sf0 < k && k <= sf0 + h0) { s_tb = tid*4;   s_ca = sf0; }
        if (sf1 < k && k <= sf1 + h1) { s_tb = tid*4+1; s_ca = sf1; }
        if (sf2 < k && k <= sf2 + h2) { s_tb = tid*4+2; s_ca = sf2; }
        if (sf3 < k && k <= sf3 + h3) { s_tb = tid*4+3; s_ca = sf3; }
        __syncthreads();
        int tb = s_tb, kk = k - s_ca;

        if (tid < 256) part[tid] = 0;
        __syncthreads();
        float ssum = 0.f;
        for (int i = tid; i < P; i += TK_THREADS) {
            unsigned key = skeys[i];
            int bin = key >> 20;
            if (bin > tb) ssum += __uint_as_float(key);
            else if (bin == tb) atomicAdd(&part[(key >> 12) & 255u], 1);
        }
        __syncthreads();
        if (tid < 256) {
            int cum = 0;
            for (int b = tid + 1; b < 256; ++b) cum += part[b];
            int h = part[tid];
            if (cum < kk && kk <= cum + h) { s_tb2 = tid; s_ca2 = cum; }
        }
        if (tid == 0) s_cnt = 0;
        __syncthreads();
        int tb2 = s_tb2, kk2 = kk - s_ca2;

        unsigned* ckeys = (unsigned*)hist;
        for (int i = tid; i < P; i += TK_THREADS) {
            unsigned key = skeys[i];
            if ((int)(key >> 20) == tb) {
                int b2 = (key >> 12) & 255u;
                if (b2 > tb2) ssum += __uint_as_float(key);
                else if (b2 == tb2) {
                    int slot = atomicAdd(&s_cnt, 1);
                    if (slot < CK_MAX) ckeys[slot] = key;
                }
            }
        }
        __syncthreads();
        int m = s_cnt; if (m > CK_MAX) m = CK_MAX;
        for (int i = tid; i < m; i += TK_THREADS) {
            unsigned key = ckeys[i];
            int rank = 0;
            for (int j = 0; j < m; ++j) {
                unsigned kj = ckeys[j];
                rank += (kj > key) || (kj == key && j < i);
            }
            if (rank < kk2) ssum += __uint_as_float(key);
        }
        #pragma unroll
        for (int off = 32; off >= 1; off >>= 1) ssum += __shfl_down(ssum, off);
        __syncthreads();
        if ((tid & 63) == 0) shf[tid >> 6] = ssum;
        __syncthreads();
        float tot = 0.f;
        for (int i = 0; i < 16; ++i) tot += shf[i];
        bsum = tot;
    }

    if (tid == 0) {
        if (bsum != 0.f) atomicAdd(&acc[2], bsum);
        __threadfence();                              // release acc adds + n_pos store
        unsigned old = atomicAdd(done, 1u);
        if (old == (unsigned)(N - 1)) {               // last block: finalize
            float a0 = atomicAdd(&acc[0], 0.f);       // atomic reads (acquire-ish)
            float a1 = atomicAdd(&acc[1], 0.f);
            float a2 = atomicAdd(&acc[2], 0.f);
            int tot = 0;
            for (int i = 0; i < N; ++i) tot += n_pos[i];
            float npos = (float)tot;
            float conf = (a2 + a1) / npos;
            float loc  = a0 / (4.f * npos);
            float loss = conf + loc;
            unsigned ub = __float_as_uint(loss);
            unsigned r = (ub + 0x7FFFu + ((ub >> 16) & 1u)) >> 16;  // bf16 RNE
            out[0] = (r << 16) | r;
        }
    }
}

extern "C" void kernel_launch(void* const* d_in, const int* in_sizes, int n_in,
                              void* d_out, int out_size, void* d_ws, size_t ws_size,
                              hipStream_t stream) {
    const float* locs   = (const float*)d_in[0];
    const float* scores = (const float*)d_in[1];
    const float* boxes  = (const float*)d_in[2];
    const int*   labels = (const int*)d_in[3];
    const float* priors = (const float*)d_in[4];

    int P = in_sizes[4] / 4;
    long long NPl = in_sizes[0] / 4;
    int N = (int)(NPl / P);
    int C = (int)((long long)in_sizes[1] / NPl);
    int O = in_sizes[3] / N;
    size_t NP = (size_t)N * P;
    int gx = (P + SBLOCK - 1) / SBLOCK;

    char* ws = (char*)d_ws;
    float*    acc    = (float*)ws;     ws += 16;
    unsigned* done   = (unsigned*)ws;  ws += 16;
    int*      n_pos  = (int*)ws;       ws += (size_t)N * 4;
    int*      pfop   = (int*)ws;       ws += (size_t)N * O * 4;
    float*    pb_loc = (float*)ws;     ws += (size_t)N * gx * 4;
    float*    pb_pce = (float*)ws;     ws += (size_t)N * gx * 4;
    int*      pb_npos= (int*)ws;       ws += (size_t)N * gx * 4;
    int*      tcarr  = (int*)ws;       ws += NP * 4;
    float*    ce_neg = (float*)ws;     ws += NP * 4;

    match_object_kernel<<<N * O, BLOCK, 0, stream>>>(boxes, priors, pfop, acc, n_pos,
                                                     done, N, P, O);
    int npb = 0;
    if (C == 81 && (P % 4) == 0 && O <= MAXO) {
        npb = gx;
        fused_staged_kernel<<<dim3(gx, N), SBLOCK, 0, stream>>>(
            boxes, priors, locs, labels, pfop, scores, ce_neg,
            pb_loc, pb_pce, pb_npos, N, P, O);
    } else {
        int gbx = (P + BLOCK - 1) / BLOCK;
        match_prior_kernel<<<dim3(gbx, N), BLOCK, 0, stream>>>(boxes, priors, locs, labels,
                                                               pfop, tcarr, acc, n_pos, N, P, O);
        loss_generic_kernel<<<(int)((NP + BLOCK - 1) / BLOCK), BLOCK, 0, stream>>>(
            scores, tcarr, ce_neg, acc, (int)NP, C);
    }
    topk_final_kernel<<<N, TK_THREADS, 0, stream>>>(ce_neg, n_pos,
                                                    pb_loc, pb_pce, pb_npos, npb,
                                                    acc, done, N, P, (unsigned*)d_out);
}